// Round 16
// baseline (7716.266 us; speedup 1.0000x reference)
//
#include <hip/hip_runtime.h>
#include <math.h>

#define TB 256      // batch
#define TT 512      // timesteps
#define TIN 128     // input size
#define TH 1024     // hidden
#define TOUT 9      // output coords
#define KD 1152     // TIN + TH

typedef _Float16 half8 __attribute__((ext_vector_type(8)));
typedef float f32x4 __attribute__((ext_vector_type(4)));

// ---- workspace layout (BYTE offsets) ----
#define OB_WHF   0ull
#define SB_WHF   (64ull*4*36*64*8*2)    // 9,437,184 B  f16 B-fragments [wcg2][nt][kc][l][j]
#define OB_WCB   (OB_WHF + SB_WHF)      // Wcombo fp32 [9][1024]
#define SB_WCB   (9ull*1024*4)
#define OB_BCB   (OB_WCB + SB_WCB)      // bcombo fp32 [9] (pad 16)
#define SB_BCB   64ull
#define OB_B0    (OB_BCB + SB_BCB)      // bias t==0 [4096] fp32
#define SB_B0    (4096ull*4)
#define OB_BC    (OB_B0 + SB_B0)        // bias t>0  [4096] fp32
#define SB_BC    (4096ull*4)
#define OB_H0    (OB_BC + SB_BC)        // hx ping [128 chunk][256 b][8] f16 (chunk-major)
#define SB_H     (256ull*1024*2)
#define OB_H1    (OB_H0 + SB_H)         // hx pong
#define OB_GC    (OB_H1 + SB_H)         // barrier counters (4 quarters x 2KB)
#define OB_END   (OB_GC + 8192ull)      // ~10.5 MB total

// fragment address for gate col `col` (0..4095), k (0..1151)
// block wcg2 = (col&1023)>>4 owns 16 h-cols; local col c = q*16 + jj, nt = q
__device__ __forceinline__ size_t frag_addr(int col, int k) {
  int q = col >> 10, hcol = col & 1023;
  int wcg2 = hcol >> 4, jj = hcol & 15;
  int kc = k >> 5, ls = (k >> 3) & 3, je = k & 7;
  return ((((size_t)wcg2 * 4 + q) * 36 + kc) * 64 + ((ls << 4) | jj)) * 8 + je;
}

// ---- agent-scope (LLC-direct) h access: write-through store, uncached load ----
__device__ __forceinline__ void st_h2_agent(_Float16* p, _Float16 v) {
  union { _Float16 h; unsigned short u; } c; c.h = v;
  __hip_atomic_store((unsigned short*)p, c.u, __ATOMIC_RELAXED, __HIP_MEMORY_SCOPE_AGENT);
}
__device__ __forceinline__ half8 ld_h16_agent(const _Float16* p) {
  union { unsigned long long u[2]; half8 h; } c;
  c.u[0] = __hip_atomic_load((const unsigned long long*)p,     __ATOMIC_RELAXED, __HIP_MEMORY_SCOPE_AGENT);
  c.u[1] = __hip_atomic_load((const unsigned long long*)p + 1, __ATOMIC_RELAXED, __HIP_MEMORY_SCOPE_AGENT);
  return c.h;
}

// ---------------- prep kernels (r5-r15 verified; frag_addr remapped r15) ----------------

__global__ __launch_bounds__(256) void k_combo(const float* __restrict__ W_h2o,
                                               const float* __restrict__ W_h2h,
                                               const float* __restrict__ b_h2h,
                                               const float* __restrict__ b_h2o,
                                               float* __restrict__ Wcombo,
                                               float* __restrict__ bcombo) {
  int gid = blockIdx.x * 256 + threadIdx.x;
  if (gid < 9 * 1024) {
    int r = gid >> 10, m = gid & 1023;
    float s = 0.f;
    for (int j = 0; j < 1024; ++j) s += W_h2o[r * 1024 + j] * W_h2h[j * 1024 + m];
    Wcombo[gid] = s;
  }
  if (gid < 9) {
    float s = b_h2o[gid];
    for (int j = 0; j < 1024; ++j) s += W_h2o[gid * 1024 + j] * b_h2h[j];
    bcombo[gid] = s;
  }
}

__global__ __launch_bounds__(256) void k_wblk(const float* __restrict__ W_hh,
                                              const float* __restrict__ W_ih,
                                              const float* __restrict__ W_h2o,
                                              const float* __restrict__ W_h2h,
                                              _Float16* __restrict__ Whf) {
  __shared__ float As2[16][68];
  __shared__ float Bs[16][68];
  __shared__ float Wio_s[64][12];
  __shared__ float Bo[9][16];
  const int tid = threadIdx.x;
  const int bm = (blockIdx.x & 15) * 64;   // m tile
  const int bc = (blockIdx.x >> 4) * 64;   // col tile
  const int tx = tid & 15, ty = tid >> 4;
  const int cl = tid >> 2, kq4 = tid & 3;

  for (int i = tid; i < 64 * 9; i += 256) {
    int row = i / 9, r = i % 9;
    Wio_s[row][r] = W_ih[(size_t)(bc + row) * 137 + 128 + r];
  }

  float acc[4][4];
#pragma unroll
  for (int i = 0; i < 4; ++i)
#pragma unroll
    for (int j = 0; j < 4; ++j) acc[i][j] = 0.f;

  for (int k0 = 0; k0 < 1024; k0 += 16) {
    __syncthreads();
    if (tid < 144) { int r = tid >> 4, kk = tid & 15; Bo[r][kk] = W_h2o[(size_t)r * 1024 + k0 + kk]; }
    { int kk = tid >> 4, q = tid & 15;
      float4 v = *(const float4*)(W_h2h + (size_t)(k0 + kk) * 1024 + bm + q * 4);
      *(float4*)&Bs[kk][q * 4] = v; }
    float4 av = *(const float4*)(W_hh + (size_t)(bc + cl) * 1024 + k0 + kq4 * 4);
    __syncthreads();
    {
      float c0 = 0.f, c1 = 0.f, c2 = 0.f, c3 = 0.f;
#pragma unroll
      for (int r = 0; r < 9; ++r) {
        float wio = Wio_s[cl][r];
        c0 += wio * Bo[r][kq4 * 4 + 0];
        c1 += wio * Bo[r][kq4 * 4 + 1];
        c2 += wio * Bo[r][kq4 * 4 + 2];
        c3 += wio * Bo[r][kq4 * 4 + 3];
      }
      As2[kq4 * 4 + 0][cl] = av.x + c0;
      As2[kq4 * 4 + 1][cl] = av.y + c1;
      As2[kq4 * 4 + 2][cl] = av.z + c2;
      As2[kq4 * 4 + 3][cl] = av.w + c3;
    }
    __syncthreads();
#pragma unroll
    for (int kk = 0; kk < 16; ++kk) {
      float4 a = *(const float4*)&As2[kk][ty * 4];
      float4 bv = *(const float4*)&Bs[kk][tx * 4];
      acc[0][0] += a.x * bv.x; acc[0][1] += a.x * bv.y; acc[0][2] += a.x * bv.z; acc[0][3] += a.x * bv.w;
      acc[1][0] += a.y * bv.x; acc[1][1] += a.y * bv.y; acc[1][2] += a.y * bv.z; acc[1][3] += a.y * bv.w;
      acc[2][0] += a.z * bv.x; acc[2][1] += a.z * bv.y; acc[2][2] += a.z * bv.z; acc[2][3] += a.z * bv.w;
      acc[3][0] += a.w * bv.x; acc[3][1] += a.w * bv.y; acc[3][2] += a.w * bv.z; acc[3][3] += a.w * bv.w;
    }
  }
#pragma unroll
  for (int i = 0; i < 4; ++i)
#pragma unroll
    for (int j = 0; j < 4; ++j) {
      int col = bc + ty * 4 + i;          // gate col
      int m = bm + tx * 4 + j;            // h index -> k = 128+m
      Whf[frag_addr(col, 128 + m)] = (_Float16)acc[i][j];
    }
}

__global__ __launch_bounds__(256) void k_bias(const float* __restrict__ b_ih,
                                              const float* __restrict__ b_hh,
                                              const float* __restrict__ W_hh,
                                              const float* __restrict__ W_ih,
                                              const float* __restrict__ b_h2h,
                                              const float* __restrict__ bcombo,
                                              float* __restrict__ b0,
                                              float* __restrict__ bconst) {
  int col = blockIdx.x * 256 + threadIdx.x;
  float base = b_ih[col] + b_hh[col];
  b0[col] = base;
  float s = 0.f;
  for (int j = 0; j < 1024; ++j) s += W_hh[(size_t)col * 1024 + j] * b_h2h[j];
#pragma unroll
  for (int r = 0; r < 9; ++r) s += W_ih[(size_t)col * 137 + 128 + r] * bcombo[r];
  bconst[col] = base + s;
}

__global__ __launch_bounds__(256) void k_fillx(const float* __restrict__ W_ih,
                                               _Float16* __restrict__ Whf) {
  int gid = blockIdx.x * 256 + threadIdx.x;   // 4096*128
  int col = gid >> 7, k = gid & 127;
  Whf[frag_addr(col, k)] = (_Float16)W_ih[(size_t)col * 137 + k];
}

__global__ void k_len(const int* __restrict__ len, float* __restrict__ dout) {
  int i = threadIdx.x;
  if (i < TB) dout[(size_t)TB * TT * TOUT + i] = (float)len[i];
}

// ---------------- persistent main kernel ----------------
// r15 structure (4 independent quarters x 64 blocks, 16 h-cols/block, Wl
// 147KB LDS, chunk-major hx, 2B write-through stores, KEEP-pinned prefetch,
// wait-window XPART + out-GEMV) with the coherence/sync chain flattened:
//   (a) h reads are UNCACHED agent loads (LLC-direct, pipelined via pinning)
//       -> NO per-step invalidate, no L2 cold-refill serialization.
//   (b) flat barrier: arrival = 1 RMW on group counter; detection = wave 0
//       lanes 0..7 poll all 8 group counters in parallel + __all ballot
//       (no lead->root hop). Bounded spin + global abort kept.

__device__ __forceinline__ float sigm(float v) { return 1.f / (1.f + __expf(-v)); }
__device__ __forceinline__ float tanh_f(float v) {
  float e2 = __expf(2.f * v);
  return (e2 - 1.f) / (e2 + 1.f);
}

#define KEEP14(a) asm volatile("" :: "v"(a[0]), "v"(a[1]), "v"(a[2]), "v"(a[3]), \
  "v"(a[4]), "v"(a[5]), "v"(a[6]), "v"(a[7]), "v"(a[8]), "v"(a[9]), "v"(a[10]), \
  "v"(a[11]), "v"(a[12]), "v"(a[13]))
#define KEEP18(a) asm volatile("" :: "v"(a[0]), "v"(a[1]), "v"(a[2]), "v"(a[3]), \
  "v"(a[4]), "v"(a[5]), "v"(a[6]), "v"(a[7]), "v"(a[8]), "v"(a[9]), "v"(a[10]), \
  "v"(a[11]), "v"(a[12]), "v"(a[13]), "v"(a[14]), "v"(a[15]), "v"(a[16]), "v"(a[17]))

__global__ __launch_bounds__(512, 2) void k_main(const float* __restrict__ x,
                                                 const _Float16* __restrict__ Whf,
                                                 const float* __restrict__ Wc,
                                                 const float* __restrict__ b0,
                                                 const float* __restrict__ bcf,
                                                 const float* __restrict__ bcombo,
                                                 _Float16* __restrict__ hA,
                                                 _Float16* __restrict__ hB,
                                                 unsigned* __restrict__ gs,
                                                 float* __restrict__ dout) {
  __shared__ _Float16 Wl[4 * 36 * 64 * 8];   // 147,456 B (64 gate cols)
  __shared__ _Float16 gbuf[64][72];          //   9,216 B
  __shared__ int sAbort;

  const int bx = blockIdx.x;
  const int qd = bx >> 6;            // quarter 0..3 (independent)
  const int wcg2 = bx & 63;          // col-group: h-cols 16*wcg2..+15
  const int B0 = qd * 64;            // batch base
  const int myb = B0 + wcg2;         // this block's out-GEMV batch
  const int grp = wcg2 >> 3;         // barrier group within quarter (8 groups x 8)
  const int tid = threadIdx.x;
  const int lane = tid & 63;
  const int wv = tid >> 6;           // 0..7
  const int mp = wv & 1, np = (wv >> 1) & 1, kh = wv >> 2;

  const size_t CH = (size_t)TB * 8;  // halfwords per 8-col chunk

  unsigned* qbase = gs + qd * 512;           // per-quarter barrier region (2KB)
  unsigned* gcnt_grp = qbase + grp * 32;     // arrival counter (own 128B line)
  unsigned* gabort = gs + 500;               // global abort flag (quarter0 tail)

  {  // stage this block's 64-col W slice (147,456 B) into LDS once
    const uint4* src = (const uint4*)(Whf + (size_t)wcg2 * (4 * 36 * 64 * 8));
    uint4* dst = (uint4*)Wl;
    for (int i = tid; i < 4 * 36 * 64 * 8 / 8; i += 512) dst[i] = src[i];
  }
  if (tid == 0) sAbort = 0;

  // bias registers for finish: cols fj and fj+8, 4 gates each, bconst + b0
  const int fb_i = tid >> 3, fj_i = tid & 7;
  const int cb = wcg2 * 16;
  float bC0 = bcf[cb + fj_i],          bC1 = bcf[1024 + cb + fj_i];
  float bC2 = bcf[2048 + cb + fj_i],   bC3 = bcf[3072 + cb + fj_i];
  float bC4 = bcf[cb + 8 + fj_i],      bC5 = bcf[1024 + cb + 8 + fj_i];
  float bC6 = bcf[2048 + cb + 8 + fj_i], bC7 = bcf[3072 + cb + 8 + fj_i];
  float bZ0 = b0[cb + fj_i],           bZ1 = b0[1024 + cb + fj_i];
  float bZ2 = b0[2048 + cb + fj_i],    bZ3 = b0[3072 + cb + fj_i];
  float bZ4 = b0[cb + 8 + fj_i],       bZ5 = b0[1024 + cb + 8 + fj_i];
  float bZ6 = b0[2048 + cb + 8 + fj_i], bZ7 = b0[3072 + cb + 8 + fj_i];
  float cs0 = 0.f, cs1 = 0.f;   // cell states for (fb_i, col fj_i) and (fb_i, col fj_i+8)
  __syncthreads();

  const _Float16* ha = hA;   // hx(t-1), zeroed by memset
  _Float16* hn = hB;

  const int bA0 = B0 + mp * 32 + (lane & 15);  // A row, M-tile 2mp
  const int bA1 = bA0 + 16;                    // A row, M-tile 2mp+1
  const int ko = (lane >> 4) * 8;              // A k offset within 32-chunk
  const int chb = lane >> 4;                   // chunk sub-offset (ko/8)
  const _Float16* wlb0 = Wl + (size_t)(2 * np) * 18432 + (size_t)lane * 8;
  const _Float16* wlb1 = wlb0 + 18432;

  // persistent accumulators: x-part(t) computed during t-1's barrier wait
  f32x4 acc00 = {0.f, 0.f, 0.f, 0.f};
  f32x4 acc01 = {0.f, 0.f, 0.f, 0.f};
  f32x4 acc10 = {0.f, 0.f, 0.f, 0.f};
  f32x4 acc11 = {0.f, 0.f, 0.f, 0.f};

#define XPART(tt) do { \
    const float* x0_ = x + ((size_t)bA0 * TT + (tt)) * TIN; \
    const float* x1_ = x + ((size_t)bA1 * TT + (tt)) * TIN; \
    _Pragma("unroll") \
    for (int i_ = 0; i_ < 4; ++i_) { \
      float4 p0 = *(const float4*)(x0_ + i_ * 32 + ko); \
      float4 p1 = *(const float4*)(x0_ + i_ * 32 + ko + 4); \
      float4 q0 = *(const float4*)(x1_ + i_ * 32 + ko); \
      float4 q1 = *(const float4*)(x1_ + i_ * 32 + ko + 4); \
      half8 v0_, v1_; \
      v0_[0] = (_Float16)p0.x; v0_[1] = (_Float16)p0.y; v0_[2] = (_Float16)p0.z; v0_[3] = (_Float16)p0.w; \
      v0_[4] = (_Float16)p1.x; v0_[5] = (_Float16)p1.y; v0_[6] = (_Float16)p1.z; v0_[7] = (_Float16)p1.w; \
      v1_[0] = (_Float16)q0.x; v1_[1] = (_Float16)q0.y; v1_[2] = (_Float16)q0.z; v1_[3] = (_Float16)q0.w; \
      v1_[4] = (_Float16)q1.x; v1_[5] = (_Float16)q1.y; v1_[6] = (_Float16)q1.z; v1_[7] = (_Float16)q1.w; \
      half8 bf0_ = *(const half8*)(wlb0 + (size_t)i_ * 512); \
      half8 bf1_ = *(const half8*)(wlb1 + (size_t)i_ * 512); \
      acc00 = __builtin_amdgcn_mfma_f32_16x16x32_f16(v0_, bf0_, acc00, 0, 0, 0); \
      acc01 = __builtin_amdgcn_mfma_f32_16x16x32_f16(v0_, bf1_, acc01, 0, 0, 0); \
      acc10 = __builtin_amdgcn_mfma_f32_16x16x32_f16(v1_, bf0_, acc10, 0, 0, 0); \
      acc11 = __builtin_amdgcn_mfma_f32_16x16x32_f16(v1_, bf1_, acc11, 0, 0, 0); \
    } \
  } while (0)

  if (kh == 0) XPART(0);   // t=0's x-part (h(-1)=0)

  for (int t = 0; t < TT; ++t) {
    // ---- h-fragment prefetch: UNCACHED (LLC-direct), pinned live via asm ----
    const _Float16* hb0 = ha + (size_t)chb * CH + (size_t)bA0 * 8;
    const _Float16* hb1 = ha + (size_t)chb * CH + (size_t)bA1 * 8;
    if (kh == 0) {
      half8 a0[14], a1[14];
#pragma unroll
      for (int i = 0; i < 14; ++i) {            // kcg = 4+i, chunk 4*i (+chb)
        a0[i] = ld_h16_agent(hb0 + (size_t)(4 * i) * CH);
        a1[i] = ld_h16_agent(hb1 + (size_t)(4 * i) * CH);
      }
      KEEP14(a0); KEEP14(a1);
      __builtin_amdgcn_sched_barrier(0);
#pragma unroll
      for (int i = 0; i < 14; ++i) {
        const int kcg = 4 + i;
        half8 bf0 = *(const half8*)(wlb0 + (size_t)kcg * 512);
        half8 bf1 = *(const half8*)(wlb1 + (size_t)kcg * 512);
        acc00 = __builtin_amdgcn_mfma_f32_16x16x32_f16(a0[i], bf0, acc00, 0, 0, 0);
        acc01 = __builtin_amdgcn_mfma_f32_16x16x32_f16(a0[i], bf1, acc01, 0, 0, 0);
        acc10 = __builtin_amdgcn_mfma_f32_16x16x32_f16(a1[i], bf0, acc10, 0, 0, 0);
        acc11 = __builtin_amdgcn_mfma_f32_16x16x32_f16(a1[i], bf1, acc11, 0, 0, 0);
      }
    } else {
      half8 a0[18], a1[18];
#pragma unroll
      for (int i = 0; i < 18; ++i) {            // kcg = 18+i, chunk 4*i+56
        a0[i] = ld_h16_agent(hb0 + (size_t)(4 * i + 56) * CH);
        a1[i] = ld_h16_agent(hb1 + (size_t)(4 * i + 56) * CH);
      }
      KEEP18(a0); KEEP18(a1);
      __builtin_amdgcn_sched_barrier(0);
#pragma unroll
      for (int i = 0; i < 18; ++i) {
        const int kcg = 18 + i;
        half8 bf0 = *(const half8*)(wlb0 + (size_t)kcg * 512);
        half8 bf1 = *(const half8*)(wlb1 + (size_t)kcg * 512);
        acc00 = __builtin_amdgcn_mfma_f32_16x16x32_f16(a0[i], bf0, acc00, 0, 0, 0);
        acc01 = __builtin_amdgcn_mfma_f32_16x16x32_f16(a0[i], bf1, acc01, 0, 0, 0);
        acc10 = __builtin_amdgcn_mfma_f32_16x16x32_f16(a1[i], bf0, acc10, 0, 0, 0);
        acc11 = __builtin_amdgcn_mfma_f32_16x16x32_f16(a1[i], bf1, acc11, 0, 0, 0);
      }
    }
    // ---- two-phase gbuf reduction: kh0 writes, kh1 adds ----
    {
      int rb0 = mp * 32 + (lane >> 4) * 4;
      int rb1 = rb0 + 16;
      int cc0 = np * 32 + (lane & 15);
      int cc1 = cc0 + 16;
      if (kh == 0) {
#pragma unroll
        for (int r = 0; r < 4; ++r) {
          gbuf[rb0 + r][cc0] = (_Float16)acc00[r];
          gbuf[rb0 + r][cc1] = (_Float16)acc01[r];
          gbuf[rb1 + r][cc0] = (_Float16)acc10[r];
          gbuf[rb1 + r][cc1] = (_Float16)acc11[r];
        }
      }
      __syncthreads();
      if (kh == 1) {
#pragma unroll
        for (int r = 0; r < 4; ++r) {
          gbuf[rb0 + r][cc0] = (_Float16)((float)gbuf[rb0 + r][cc0] + acc00[r]);
          gbuf[rb0 + r][cc1] = (_Float16)((float)gbuf[rb0 + r][cc1] + acc01[r]);
          gbuf[rb1 + r][cc0] = (_Float16)((float)gbuf[rb1 + r][cc0] + acc10[r]);
          gbuf[rb1 + r][cc1] = (_Float16)((float)gbuf[rb1 + r][cc1] + acc11[r]);
        }
      }
      __syncthreads();
    }

    // ---- LSTM finish: thread (fb_i, fj_i) handles cols fj_i and fj_i+8 ----
    {
      const bool later = (t > 0);
      float b_0 = later ? bC0 : bZ0, b_1 = later ? bC1 : bZ1;
      float b_2 = later ? bC2 : bZ2, b_3 = later ? bC3 : bZ3;
      float b_4 = later ? bC4 : bZ4, b_5 = later ? bC5 : bZ5;
      float b_6 = later ? bC6 : bZ6, b_7 = later ? bC7 : bZ7;
      float vi = (float)gbuf[fb_i][fj_i]      + b_0;
      float vf = (float)gbuf[fb_i][16 + fj_i] + b_1;
      float vg = (float)gbuf[fb_i][32 + fj_i] + b_2;
      float vo = (float)gbuf[fb_i][48 + fj_i] + b_3;
      float ig = sigm(vi), fg = sigm(vf), gg = tanh_f(vg), og = sigm(vo);
      float cn = fg * cs0 + ig * gg;
      cs0 = cn;
      st_h2_agent(hn + (size_t)(2 * wcg2) * CH + (size_t)(B0 + fb_i) * 8 + fj_i,
                  (_Float16)(og * tanh_f(cn)));
      float vi2 = (float)gbuf[fb_i][8 + fj_i]  + b_4;
      float vf2 = (float)gbuf[fb_i][24 + fj_i] + b_5;
      float vg2 = (float)gbuf[fb_i][40 + fj_i] + b_6;
      float vo2 = (float)gbuf[fb_i][56 + fj_i] + b_7;
      float ig2 = sigm(vi2), fg2 = sigm(vf2), gg2 = tanh_f(vg2), og2 = sigm(vo2);
      float cn2 = fg2 * cs1 + ig2 * gg2;
      cs1 = cn2;
      st_h2_agent(hn + (size_t)(2 * wcg2 + 1) * CH + (size_t)(B0 + fb_i) * 8 + fj_i,
                  (_Float16)(og2 * tanh_f(cn2)));
    }
    __threadfence_block();   // drain own vmcnt: stores at LLC
    __syncthreads();         // whole block drained

    // ---- flat barrier arrival: one RMW on this block's group counter ----
    if (tid == 0)
      __hip_atomic_fetch_add(gcnt_grp, 1u, __ATOMIC_RELAXED, __HIP_MEMORY_SCOPE_AGENT);

    // ---- wait-window work 1: out(t-1) GEMV (uncached h, cached Wc) ----
    if (t > 0) {
      const _Float16* hxb = ha + (size_t)myb * 8;
      {
        const float* wcp = Wc + (size_t)wv * 1024;
        float s = 0.f;
#pragma unroll
        for (int p = 0; p < 2; ++p) {
          int ch = 2 * lane + p;
          half8 hv = ld_h16_agent(hxb + (size_t)ch * CH);
          float4 wa = *(const float4*)(wcp + ch * 8);
          float4 wb = *(const float4*)(wcp + ch * 8 + 4);
          s += (float)hv[0] * wa.x + (float)hv[1] * wa.y + (float)hv[2] * wa.z + (float)hv[3] * wa.w
             + (float)hv[4] * wb.x + (float)hv[5] * wb.y + (float)hv[6] * wb.z + (float)hv[7] * wb.w;
        }
#pragma unroll
        for (int off = 32; off > 0; off >>= 1) s += __shfl_down(s, off, 64);
        if (lane == 0) dout[((size_t)myb * TT + (t - 1)) * TOUT + wv] = s + bcombo[wv];
      }
      if (wv == 0) {
        const float* wcp = Wc + 8 * 1024;
        float s = 0.f;
#pragma unroll
        for (int p = 0; p < 2; ++p) {
          int ch = 2 * lane + p;
          half8 hv = ld_h16_agent(hxb + (size_t)ch * CH);
          float4 wa = *(const float4*)(wcp + ch * 8);
          float4 wb = *(const float4*)(wcp + ch * 8 + 4);
          s += (float)hv[0] * wa.x + (float)hv[1] * wa.y + (float)hv[2] * wa.z + (float)hv[3] * wa.w
             + (float)hv[4] * wb.x + (float)hv[5] * wb.y + (float)hv[6] * wb.z + (float)hv[7] * wb.w;
        }
#pragma unroll
        for (int off = 32; off > 0; off >>= 1) s += __shfl_down(s, off, 64);
        if (lane == 0) dout[((size_t)myb * TT + (t - 1)) * TOUT + 8] = s + bcombo[8];
      }
    }

    // ---- wait-window work 2: x-part of gates(t+1) into fresh acc ----
    acc00 = (f32x4){0.f, 0.f, 0.f, 0.f};
    acc01 = (f32x4){0.f, 0.f, 0.f, 0.f};
    acc10 = (f32x4){0.f, 0.f, 0.f, 0.f};
    acc11 = (f32x4){0.f, 0.f, 0.f, 0.f};
    if (kh == 0 && t + 1 < TT) XPART(t + 1);

    // ---- flat poll: wave 0 lanes 0..7 watch all 8 group counters ----
    if (wv == 0) {
      const unsigned tgt = (unsigned)(t + 1) * 8u;
      unsigned guard = 0;
      bool ab = false;
      for (;;) {
        unsigned v = tgt;
        if (lane < 8)
          v = __hip_atomic_load(qbase + lane * 32, __ATOMIC_RELAXED, __HIP_MEMORY_SCOPE_AGENT);
        if (__all((int)(v >= tgt))) break;
        __builtin_amdgcn_s_sleep(1);
        ++guard;
        unsigned af = 0;
        if ((guard & 255u) == 0u && lane == 0)
          af = __hip_atomic_load(gabort, __ATOMIC_RELAXED, __HIP_MEMORY_SCOPE_AGENT);
        if (__any((int)(af != 0u))) { ab = true; break; }
        if (guard > 200000u) {
          if (lane == 0)
            __hip_atomic_store(gabort, 1u, __ATOMIC_RELAXED, __HIP_MEMORY_SCOPE_AGENT);
          ab = true; break;
        }
      }
      if (ab && lane == 0) sAbort = 1;
    }
    __syncthreads();
    if (sAbort) return;   // wrong answer beats a wedged GPU

    const _Float16* tp = ha; ha = hn; hn = (_Float16*)tp;
  }

  // ---- epilogue: out(TT-1) for this block's batch from final h ----
  {
    const _Float16* hxb = ha + (size_t)myb * 8;
    {
      const float* wcp = Wc + (size_t)wv * 1024;
      float s = 0.f;
#pragma unroll
      for (int p = 0; p < 2; ++p) {
        int ch = 2 * lane + p;
        half8 hv = ld_h16_agent(hxb + (size_t)ch * CH);
        float4 wa = *(const float4*)(wcp + ch * 8);
        float4 wb = *(const float4*)(wcp + ch * 8 + 4);
        s += (float)hv[0] * wa.x + (float)hv[1] * wa.y + (float)hv[2] * wa.z + (float)hv[3] * wa.w
           + (float)hv[4] * wb.x + (float)hv[5] * wb.y + (float)hv[6] * wb.z + (float)hv[7] * wb.w;
      }
#pragma unroll
      for (int off = 32; off > 0; off >>= 1) s += __shfl_down(s, off, 64);
      if (lane == 0) dout[((size_t)myb * TT + (TT - 1)) * TOUT + wv] = s + bcombo[wv];
    }
    if (wv == 0) {
      const float* wcp = Wc + 8 * 1024;
      float s = 0.f;
#pragma unroll
      for (int p = 0; p < 2; ++p) {
        int ch = 2 * lane + p;
        half8 hv = ld_h16_agent(hxb + (size_t)ch * CH);
        float4 wa = *(const float4*)(wcp + ch * 8);
        float4 wb = *(const float4*)(wcp + ch * 8 + 4);
        s += (float)hv[0] * wa.x + (float)hv[1] * wa.y + (float)hv[2] * wa.z + (float)hv[3] * wa.w
           + (float)hv[4] * wb.x + (float)hv[5] * wb.y + (float)hv[6] * wb.z + (float)hv[7] * wb.w;
      }
#pragma unroll
      for (int off = 32; off > 0; off >>= 1) s += __shfl_down(s, off, 64);
      if (lane == 0) dout[((size_t)myb * TT + (TT - 1)) * TOUT + 8] = s + bcombo[8];
    }
  }
}

// ---------------- launch ----------------

extern "C" void kernel_launch(void* const* d_in, const int* in_sizes, int n_in,
                              void* d_out, int out_size, void* d_ws, size_t ws_size,
                              hipStream_t stream) {
  if (ws_size < OB_END) return;   // clean fail, no OOB

  const float* x     = (const float*)d_in[0];
  const float* W_ih  = (const float*)d_in[1];
  const float* b_ih  = (const float*)d_in[2];
  const float* W_hh  = (const float*)d_in[3];
  const float* b_hh  = (const float*)d_in[4];
  const float* W_h2h = (const float*)d_in[5];
  const float* b_h2h = (const float*)d_in[6];
  const float* W_h2o = (const float*)d_in[7];
  const float* b_h2o = (const float*)d_in[8];
  const int*   lens  = (const int*)d_in[9];

  char* ws = (char*)d_ws;
  float* dout    = (float*)d_out;
  _Float16* Whf  = (_Float16*)(ws + OB_WHF);
  float* Wcombo  = (float*)(ws + OB_WCB);
  float* bcombo  = (float*)(ws + OB_BCB);
  float* b0      = (float*)(ws + OB_B0);
  float* bconst  = (float*)(ws + OB_BC);
  _Float16* h0   = (_Float16*)(ws + OB_H0);
  _Float16* h1   = (_Float16*)(ws + OB_H1);
  unsigned* gs   = (unsigned*)(ws + OB_GC);

  // zero hx ping-pong + barrier counters every call (graph-replay safe)
  hipMemsetAsync((void*)(ws + OB_H0), 0, OB_END - OB_H0, stream);

  k_combo<<<36, 256, 0, stream>>>(W_h2o, W_h2h, b_h2h, b_h2o, Wcombo, bcombo);
  k_wblk<<<1024, 256, 0, stream>>>(W_hh, W_ih, W_h2o, W_h2h, Whf);
  k_bias<<<16, 256, 0, stream>>>(b_ih, b_hh, W_hh, W_ih, b_h2h, bcombo, b0, bconst);
  k_fillx<<<2048, 256, 0, stream>>>(W_ih, Whf);
  k_len<<<1, 256, 0, stream>>>(lens, dout);

  k_main<<<256, 512, 0, stream>>>(x, Whf, Wcombo, b0, bconst, bcombo, h0, h1, gs, dout);
}

// Round 17
// 4783.354 us; speedup vs baseline: 1.6131x; 1.6131x over previous
//
#include <hip/hip_runtime.h>
#include <math.h>

#define TB 256      // batch
#define TT 512      // timesteps
#define TIN 128     // input size
#define TH 1024     // hidden
#define TOUT 9      // output coords
#define KD 1152     // TIN + TH

typedef _Float16 half8 __attribute__((ext_vector_type(8)));
typedef float f32x4 __attribute__((ext_vector_type(4)));

// ---- workspace layout (BYTE offsets) ----
#define OB_WHF   0ull
#define SB_WHF   (64ull*4*36*64*8*2)    // 9,437,184 B  f16 B-fragments [wcg2][nt][kc][l][j]
#define OB_WCB   (OB_WHF + SB_WHF)      // Wcombo fp32 [9][1024]
#define SB_WCB   (9ull*1024*4)
#define OB_BCB   (OB_WCB + SB_WCB)      // bcombo fp32 [9] (pad 16)
#define SB_BCB   64ull
#define OB_B0    (OB_BCB + SB_BCB)      // bias t==0 [4096] fp32
#define SB_B0    (4096ull*4)
#define OB_BC    (OB_B0 + SB_B0)        // bias t>0  [4096] fp32
#define SB_BC    (4096ull*4)
#define OB_H0    (OB_BC + SB_BC)        // hx ping [128 chunk][256 b][8] f16 (chunk-major)
#define SB_H     (256ull*1024*2)
#define OB_H1    (OB_H0 + SB_H)         // hx pong
#define OB_GC    (OB_H1 + SB_H)         // barrier counters (4 quarters x 2KB)
#define OB_END   (OB_GC + 8192ull)      // ~10.5 MB total

// fragment address for gate col `col` (0..4095), k (0..1151)
// block wcg2 = (col&1023)>>4 owns 16 h-cols; local col c = q*16 + jj, nt = q
__device__ __forceinline__ size_t frag_addr(int col, int k) {
  int q = col >> 10, hcol = col & 1023;
  int wcg2 = hcol >> 4, jj = hcol & 15;
  int kc = k >> 5, ls = (k >> 3) & 3, je = k & 7;
  return ((((size_t)wcg2 * 4 + q) * 36 + kc) * 64 + ((ls << 4) | jj)) * 8 + je;
}

// ---- agent-scope (LLC write-through) 2B h store ----
__device__ __forceinline__ void st_h2_agent(_Float16* p, _Float16 v) {
  union { _Float16 h; unsigned short u; } c; c.h = v;
  __hip_atomic_store((unsigned short*)p, c.u, __ATOMIC_RELAXED, __HIP_MEMORY_SCOPE_AGENT);
}

// ---------------- prep kernels (r5-r15 verified; frag_addr remapped r15) ----------------

__global__ __launch_bounds__(256) void k_combo(const float* __restrict__ W_h2o,
                                               const float* __restrict__ W_h2h,
                                               const float* __restrict__ b_h2h,
                                               const float* __restrict__ b_h2o,
                                               float* __restrict__ Wcombo,
                                               float* __restrict__ bcombo) {
  int gid = blockIdx.x * 256 + threadIdx.x;
  if (gid < 9 * 1024) {
    int r = gid >> 10, m = gid & 1023;
    float s = 0.f;
    for (int j = 0; j < 1024; ++j) s += W_h2o[r * 1024 + j] * W_h2h[j * 1024 + m];
    Wcombo[gid] = s;
  }
  if (gid < 9) {
    float s = b_h2o[gid];
    for (int j = 0; j < 1024; ++j) s += W_h2o[gid * 1024 + j] * b_h2h[j];
    bcombo[gid] = s;
  }
}

__global__ __launch_bounds__(256) void k_wblk(const float* __restrict__ W_hh,
                                              const float* __restrict__ W_ih,
                                              const float* __restrict__ W_h2o,
                                              const float* __restrict__ W_h2h,
                                              _Float16* __restrict__ Whf) {
  __shared__ float As2[16][68];
  __shared__ float Bs[16][68];
  __shared__ float Wio_s[64][12];
  __shared__ float Bo[9][16];
  const int tid = threadIdx.x;
  const int bm = (blockIdx.x & 15) * 64;   // m tile
  const int bc = (blockIdx.x >> 4) * 64;   // col tile
  const int tx = tid & 15, ty = tid >> 4;
  const int cl = tid >> 2, kq4 = tid & 3;

  for (int i = tid; i < 64 * 9; i += 256) {
    int row = i / 9, r = i % 9;
    Wio_s[row][r] = W_ih[(size_t)(bc + row) * 137 + 128 + r];
  }

  float acc[4][4];
#pragma unroll
  for (int i = 0; i < 4; ++i)
#pragma unroll
    for (int j = 0; j < 4; ++j) acc[i][j] = 0.f;

  for (int k0 = 0; k0 < 1024; k0 += 16) {
    __syncthreads();
    if (tid < 144) { int r = tid >> 4, kk = tid & 15; Bo[r][kk] = W_h2o[(size_t)r * 1024 + k0 + kk]; }
    { int kk = tid >> 4, q = tid & 15;
      float4 v = *(const float4*)(W_h2h + (size_t)(k0 + kk) * 1024 + bm + q * 4);
      *(float4*)&Bs[kk][q * 4] = v; }
    float4 av = *(const float4*)(W_hh + (size_t)(bc + cl) * 1024 + k0 + kq4 * 4);
    __syncthreads();
    {
      float c0 = 0.f, c1 = 0.f, c2 = 0.f, c3 = 0.f;
#pragma unroll
      for (int r = 0; r < 9; ++r) {
        float wio = Wio_s[cl][r];
        c0 += wio * Bo[r][kq4 * 4 + 0];
        c1 += wio * Bo[r][kq4 * 4 + 1];
        c2 += wio * Bo[r][kq4 * 4 + 2];
        c3 += wio * Bo[r][kq4 * 4 + 3];
      }
      As2[kq4 * 4 + 0][cl] = av.x + c0;
      As2[kq4 * 4 + 1][cl] = av.y + c1;
      As2[kq4 * 4 + 2][cl] = av.z + c2;
      As2[kq4 * 4 + 3][cl] = av.w + c3;
    }
    __syncthreads();
#pragma unroll
    for (int kk = 0; kk < 16; ++kk) {
      float4 a = *(const float4*)&As2[kk][ty * 4];
      float4 bv = *(const float4*)&Bs[kk][tx * 4];
      acc[0][0] += a.x * bv.x; acc[0][1] += a.x * bv.y; acc[0][2] += a.x * bv.z; acc[0][3] += a.x * bv.w;
      acc[1][0] += a.y * bv.x; acc[1][1] += a.y * bv.y; acc[1][2] += a.y * bv.z; acc[1][3] += a.y * bv.w;
      acc[2][0] += a.z * bv.x; acc[2][1] += a.z * bv.y; acc[2][2] += a.z * bv.z; acc[2][3] += a.z * bv.w;
      acc[3][0] += a.w * bv.x; acc[3][1] += a.w * bv.y; acc[3][2] += a.w * bv.z; acc[3][3] += a.w * bv.w;
    }
  }
#pragma unroll
  for (int i = 0; i < 4; ++i)
#pragma unroll
    for (int j = 0; j < 4; ++j) {
      int col = bc + ty * 4 + i;          // gate col
      int m = bm + tx * 4 + j;            // h index -> k = 128+m
      Whf[frag_addr(col, 128 + m)] = (_Float16)acc[i][j];
    }
}

__global__ __launch_bounds__(256) void k_bias(const float* __restrict__ b_ih,
                                              const float* __restrict__ b_hh,
                                              const float* __restrict__ W_hh,
                                              const float* __restrict__ W_ih,
                                              const float* __restrict__ b_h2h,
                                              const float* __restrict__ bcombo,
                                              float* __restrict__ b0,
                                              float* __restrict__ bconst) {
  int col = blockIdx.x * 256 + threadIdx.x;
  float base = b_ih[col] + b_hh[col];
  b0[col] = base;
  float s = 0.f;
  for (int j = 0; j < 1024; ++j) s += W_hh[(size_t)col * 1024 + j] * b_h2h[j];
#pragma unroll
  for (int r = 0; r < 9; ++r) s += W_ih[(size_t)col * 137 + 128 + r] * bcombo[r];
  bconst[col] = base + s;
}

__global__ __launch_bounds__(256) void k_fillx(const float* __restrict__ W_ih,
                                               _Float16* __restrict__ Whf) {
  int gid = blockIdx.x * 256 + threadIdx.x;   // 4096*128
  int col = gid >> 7, k = gid & 127;
  Whf[frag_addr(col, k)] = (_Float16)W_ih[(size_t)col * 137 + k];
}

__global__ void k_len(const int* __restrict__ len, float* __restrict__ dout) {
  int i = threadIdx.x;
  if (i < TB) dout[(size_t)TB * TT * TOUT + i] = (float)len[i];
}

// ---------------- persistent main kernel ----------------
// r15 structure VERBATIM (cached h reads + invalidate-only ACQUIRE, chunk-
// major hx, 2B write-through stores, KEEP-pinned prefetch, two-phase gbuf,
// register biases, wait-window XPART + out-GEMV, 4 independent quarters)
// with ONLY the barrier flattened (r16's part b, isolated):
//   arrival = 1 RMW on group counter (no lead->root hop);
//   detection = wave 0 lanes 0..7 poll all 8 group counters + __all;
//   post-release: lane 0 ACQUIRE load -> buffer_inv (coherence for cached h).

__device__ __forceinline__ float sigm(float v) { return 1.f / (1.f + __expf(-v)); }
__device__ __forceinline__ float tanh_f(float v) {
  float e2 = __expf(2.f * v);
  return (e2 - 1.f) / (e2 + 1.f);
}

#define KEEP14(a) asm volatile("" :: "v"(a[0]), "v"(a[1]), "v"(a[2]), "v"(a[3]), \
  "v"(a[4]), "v"(a[5]), "v"(a[6]), "v"(a[7]), "v"(a[8]), "v"(a[9]), "v"(a[10]), \
  "v"(a[11]), "v"(a[12]), "v"(a[13]))
#define KEEP18(a) asm volatile("" :: "v"(a[0]), "v"(a[1]), "v"(a[2]), "v"(a[3]), \
  "v"(a[4]), "v"(a[5]), "v"(a[6]), "v"(a[7]), "v"(a[8]), "v"(a[9]), "v"(a[10]), \
  "v"(a[11]), "v"(a[12]), "v"(a[13]), "v"(a[14]), "v"(a[15]), "v"(a[16]), "v"(a[17]))

__global__ __launch_bounds__(512, 2) void k_main(const float* __restrict__ x,
                                                 const _Float16* __restrict__ Whf,
                                                 const float* __restrict__ Wc,
                                                 const float* __restrict__ b0,
                                                 const float* __restrict__ bcf,
                                                 const float* __restrict__ bcombo,
                                                 _Float16* __restrict__ hA,
                                                 _Float16* __restrict__ hB,
                                                 unsigned* __restrict__ gs,
                                                 float* __restrict__ dout) {
  __shared__ _Float16 Wl[4 * 36 * 64 * 8];   // 147,456 B (64 gate cols)
  __shared__ _Float16 gbuf[64][72];          //   9,216 B
  __shared__ int sAbort;

  const int bx = blockIdx.x;
  const int qd = bx >> 6;            // quarter 0..3 (independent)
  const int wcg2 = bx & 63;          // col-group: h-cols 16*wcg2..+15
  const int B0 = qd * 64;            // batch base
  const int myb = B0 + wcg2;         // this block's out-GEMV batch
  const int grp = wcg2 >> 3;         // barrier group within quarter (8 groups x 8)
  const int tid = threadIdx.x;
  const int lane = tid & 63;
  const int wv = tid >> 6;           // 0..7
  const int mp = wv & 1, np = (wv >> 1) & 1, kh = wv >> 2;

  const size_t CH = (size_t)TB * 8;  // halfwords per 8-col chunk

  unsigned* qbase = gs + qd * 512;           // per-quarter barrier region (2KB)
  unsigned* gcnt_grp = qbase + grp * 32;     // arrival counter (own 128B line)
  unsigned* gabort = gs + 500;               // global abort flag (quarter0 tail)

  {  // stage this block's 64-col W slice (147,456 B) into LDS once
    const uint4* src = (const uint4*)(Whf + (size_t)wcg2 * (4 * 36 * 64 * 8));
    uint4* dst = (uint4*)Wl;
    for (int i = tid; i < 4 * 36 * 64 * 8 / 8; i += 512) dst[i] = src[i];
  }
  if (tid == 0) sAbort = 0;

  // bias registers for finish: cols fj and fj+8, 4 gates each, bconst + b0
  const int fb_i = tid >> 3, fj_i = tid & 7;
  const int cb = wcg2 * 16;
  float bC0 = bcf[cb + fj_i],          bC1 = bcf[1024 + cb + fj_i];
  float bC2 = bcf[2048 + cb + fj_i],   bC3 = bcf[3072 + cb + fj_i];
  float bC4 = bcf[cb + 8 + fj_i],      bC5 = bcf[1024 + cb + 8 + fj_i];
  float bC6 = bcf[2048 + cb + 8 + fj_i], bC7 = bcf[3072 + cb + 8 + fj_i];
  float bZ0 = b0[cb + fj_i],           bZ1 = b0[1024 + cb + fj_i];
  float bZ2 = b0[2048 + cb + fj_i],    bZ3 = b0[3072 + cb + fj_i];
  float bZ4 = b0[cb + 8 + fj_i],       bZ5 = b0[1024 + cb + 8 + fj_i];
  float bZ6 = b0[2048 + cb + 8 + fj_i], bZ7 = b0[3072 + cb + 8 + fj_i];
  float cs0 = 0.f, cs1 = 0.f;   // cell states for (fb_i, col fj_i) and (fb_i, col fj_i+8)
  __syncthreads();

  const _Float16* ha = hA;   // hx(t-1), zeroed by memset
  _Float16* hn = hB;

  const int bA0 = B0 + mp * 32 + (lane & 15);  // A row, M-tile 2mp
  const int bA1 = bA0 + 16;                    // A row, M-tile 2mp+1
  const int ko = (lane >> 4) * 8;              // A k offset within 32-chunk
  const int chb = lane >> 4;                   // chunk sub-offset (ko/8)
  const _Float16* wlb0 = Wl + (size_t)(2 * np) * 18432 + (size_t)lane * 8;
  const _Float16* wlb1 = wlb0 + 18432;

  // persistent accumulators: x-part(t) computed during t-1's barrier wait
  f32x4 acc00 = {0.f, 0.f, 0.f, 0.f};
  f32x4 acc01 = {0.f, 0.f, 0.f, 0.f};
  f32x4 acc10 = {0.f, 0.f, 0.f, 0.f};
  f32x4 acc11 = {0.f, 0.f, 0.f, 0.f};

#define XPART(tt) do { \
    const float* x0_ = x + ((size_t)bA0 * TT + (tt)) * TIN; \
    const float* x1_ = x + ((size_t)bA1 * TT + (tt)) * TIN; \
    _Pragma("unroll") \
    for (int i_ = 0; i_ < 4; ++i_) { \
      float4 p0 = *(const float4*)(x0_ + i_ * 32 + ko); \
      float4 p1 = *(const float4*)(x0_ + i_ * 32 + ko + 4); \
      float4 q0 = *(const float4*)(x1_ + i_ * 32 + ko); \
      float4 q1 = *(const float4*)(x1_ + i_ * 32 + ko + 4); \
      half8 v0_, v1_; \
      v0_[0] = (_Float16)p0.x; v0_[1] = (_Float16)p0.y; v0_[2] = (_Float16)p0.z; v0_[3] = (_Float16)p0.w; \
      v0_[4] = (_Float16)p1.x; v0_[5] = (_Float16)p1.y; v0_[6] = (_Float16)p1.z; v0_[7] = (_Float16)p1.w; \
      v1_[0] = (_Float16)q0.x; v1_[1] = (_Float16)q0.y; v1_[2] = (_Float16)q0.z; v1_[3] = (_Float16)q0.w; \
      v1_[4] = (_Float16)q1.x; v1_[5] = (_Float16)q1.y; v1_[6] = (_Float16)q1.z; v1_[7] = (_Float16)q1.w; \
      half8 bf0_ = *(const half8*)(wlb0 + (size_t)i_ * 512); \
      half8 bf1_ = *(const half8*)(wlb1 + (size_t)i_ * 512); \
      acc00 = __builtin_amdgcn_mfma_f32_16x16x32_f16(v0_, bf0_, acc00, 0, 0, 0); \
      acc01 = __builtin_amdgcn_mfma_f32_16x16x32_f16(v0_, bf1_, acc01, 0, 0, 0); \
      acc10 = __builtin_amdgcn_mfma_f32_16x16x32_f16(v1_, bf0_, acc10, 0, 0, 0); \
      acc11 = __builtin_amdgcn_mfma_f32_16x16x32_f16(v1_, bf1_, acc11, 0, 0, 0); \
    } \
  } while (0)

  if (kh == 0) XPART(0);   // t=0's x-part (h(-1)=0)

  for (int t = 0; t < TT; ++t) {
    // ---- h-fragment prefetch (cached, post-inv), pinned live via asm ----
    const _Float16* hb0 = ha + (size_t)chb * CH + (size_t)bA0 * 8;
    const _Float16* hb1 = ha + (size_t)chb * CH + (size_t)bA1 * 8;
    if (kh == 0) {
      half8 a0[14], a1[14];
#pragma unroll
      for (int i = 0; i < 14; ++i) {            // kcg = 4+i, chunk 4*i (+chb)
        a0[i] = *(const half8*)(hb0 + (size_t)(4 * i) * CH);
        a1[i] = *(const half8*)(hb1 + (size_t)(4 * i) * CH);
      }
      KEEP14(a0); KEEP14(a1);
      __builtin_amdgcn_sched_barrier(0);
#pragma unroll
      for (int i = 0; i < 14; ++i) {
        const int kcg = 4 + i;
        half8 bf0 = *(const half8*)(wlb0 + (size_t)kcg * 512);
        half8 bf1 = *(const half8*)(wlb1 + (size_t)kcg * 512);
        acc00 = __builtin_amdgcn_mfma_f32_16x16x32_f16(a0[i], bf0, acc00, 0, 0, 0);
        acc01 = __builtin_amdgcn_mfma_f32_16x16x32_f16(a0[i], bf1, acc01, 0, 0, 0);
        acc10 = __builtin_amdgcn_mfma_f32_16x16x32_f16(a1[i], bf0, acc10, 0, 0, 0);
        acc11 = __builtin_amdgcn_mfma_f32_16x16x32_f16(a1[i], bf1, acc11, 0, 0, 0);
      }
    } else {
      half8 a0[18], a1[18];
#pragma unroll
      for (int i = 0; i < 18; ++i) {            // kcg = 18+i, chunk 4*i+56
        a0[i] = *(const half8*)(hb0 + (size_t)(4 * i + 56) * CH);
        a1[i] = *(const half8*)(hb1 + (size_t)(4 * i + 56) * CH);
      }
      KEEP18(a0); KEEP18(a1);
      __builtin_amdgcn_sched_barrier(0);
#pragma unroll
      for (int i = 0; i < 18; ++i) {
        const int kcg = 18 + i;
        half8 bf0 = *(const half8*)(wlb0 + (size_t)kcg * 512);
        half8 bf1 = *(const half8*)(wlb1 + (size_t)kcg * 512);
        acc00 = __builtin_amdgcn_mfma_f32_16x16x32_f16(a0[i], bf0, acc00, 0, 0, 0);
        acc01 = __builtin_amdgcn_mfma_f32_16x16x32_f16(a0[i], bf1, acc01, 0, 0, 0);
        acc10 = __builtin_amdgcn_mfma_f32_16x16x32_f16(a1[i], bf0, acc10, 0, 0, 0);
        acc11 = __builtin_amdgcn_mfma_f32_16x16x32_f16(a1[i], bf1, acc11, 0, 0, 0);
      }
    }
    // ---- two-phase gbuf reduction: kh0 writes, kh1 adds ----
    {
      int rb0 = mp * 32 + (lane >> 4) * 4;
      int rb1 = rb0 + 16;
      int cc0 = np * 32 + (lane & 15);
      int cc1 = cc0 + 16;
      if (kh == 0) {
#pragma unroll
        for (int r = 0; r < 4; ++r) {
          gbuf[rb0 + r][cc0] = (_Float16)acc00[r];
          gbuf[rb0 + r][cc1] = (_Float16)acc01[r];
          gbuf[rb1 + r][cc0] = (_Float16)acc10[r];
          gbuf[rb1 + r][cc1] = (_Float16)acc11[r];
        }
      }
      __syncthreads();
      if (kh == 1) {
#pragma unroll
        for (int r = 0; r < 4; ++r) {
          gbuf[rb0 + r][cc0] = (_Float16)((float)gbuf[rb0 + r][cc0] + acc00[r]);
          gbuf[rb0 + r][cc1] = (_Float16)((float)gbuf[rb0 + r][cc1] + acc01[r]);
          gbuf[rb1 + r][cc0] = (_Float16)((float)gbuf[rb1 + r][cc0] + acc10[r]);
          gbuf[rb1 + r][cc1] = (_Float16)((float)gbuf[rb1 + r][cc1] + acc11[r]);
        }
      }
      __syncthreads();
    }

    // ---- LSTM finish: thread (fb_i, fj_i) handles cols fj_i and fj_i+8 ----
    {
      const bool later = (t > 0);
      float b_0 = later ? bC0 : bZ0, b_1 = later ? bC1 : bZ1;
      float b_2 = later ? bC2 : bZ2, b_3 = later ? bC3 : bZ3;
      float b_4 = later ? bC4 : bZ4, b_5 = later ? bC5 : bZ5;
      float b_6 = later ? bC6 : bZ6, b_7 = later ? bC7 : bZ7;
      float vi = (float)gbuf[fb_i][fj_i]      + b_0;
      float vf = (float)gbuf[fb_i][16 + fj_i] + b_1;
      float vg = (float)gbuf[fb_i][32 + fj_i] + b_2;
      float vo = (float)gbuf[fb_i][48 + fj_i] + b_3;
      float ig = sigm(vi), fg = sigm(vf), gg = tanh_f(vg), og = sigm(vo);
      float cn = fg * cs0 + ig * gg;
      cs0 = cn;
      st_h2_agent(hn + (size_t)(2 * wcg2) * CH + (size_t)(B0 + fb_i) * 8 + fj_i,
                  (_Float16)(og * tanh_f(cn)));
      float vi2 = (float)gbuf[fb_i][8 + fj_i]  + b_4;
      float vf2 = (float)gbuf[fb_i][24 + fj_i] + b_5;
      float vg2 = (float)gbuf[fb_i][40 + fj_i] + b_6;
      float vo2 = (float)gbuf[fb_i][56 + fj_i] + b_7;
      float ig2 = sigm(vi2), fg2 = sigm(vf2), gg2 = tanh_f(vg2), og2 = sigm(vo2);
      float cn2 = fg2 * cs1 + ig2 * gg2;
      cs1 = cn2;
      st_h2_agent(hn + (size_t)(2 * wcg2 + 1) * CH + (size_t)(B0 + fb_i) * 8 + fj_i,
                  (_Float16)(og2 * tanh_f(cn2)));
    }
    __threadfence_block();   // drain own vmcnt: stores at LLC
    __syncthreads();         // whole block drained

    // ---- flat barrier arrival: one RMW on this block's group counter ----
    if (tid == 0)
      __hip_atomic_fetch_add(gcnt_grp, 1u, __ATOMIC_RELAXED, __HIP_MEMORY_SCOPE_AGENT);

    // ---- wait-window work 1: out(t-1) GEMV (cached h, cached Wc) ----
    if (t > 0) {
      const _Float16* hxb = ha + (size_t)myb * 8;
      {
        const float* wcp = Wc + (size_t)wv * 1024;
        float s = 0.f;
#pragma unroll
        for (int p = 0; p < 2; ++p) {
          int ch = 2 * lane + p;
          half8 hv = *(const half8*)(hxb + (size_t)ch * CH);
          float4 wa = *(const float4*)(wcp + ch * 8);
          float4 wb = *(const float4*)(wcp + ch * 8 + 4);
          s += (float)hv[0] * wa.x + (float)hv[1] * wa.y + (float)hv[2] * wa.z + (float)hv[3] * wa.w
             + (float)hv[4] * wb.x + (float)hv[5] * wb.y + (float)hv[6] * wb.z + (float)hv[7] * wb.w;
        }
#pragma unroll
        for (int off = 32; off > 0; off >>= 1) s += __shfl_down(s, off, 64);
        if (lane == 0) dout[((size_t)myb * TT + (t - 1)) * TOUT + wv] = s + bcombo[wv];
      }
      if (wv == 0) {
        const float* wcp = Wc + 8 * 1024;
        float s = 0.f;
#pragma unroll
        for (int p = 0; p < 2; ++p) {
          int ch = 2 * lane + p;
          half8 hv = *(const half8*)(hxb + (size_t)ch * CH);
          float4 wa = *(const float4*)(wcp + ch * 8);
          float4 wb = *(const float4*)(wcp + ch * 8 + 4);
          s += (float)hv[0] * wa.x + (float)hv[1] * wa.y + (float)hv[2] * wa.z + (float)hv[3] * wa.w
             + (float)hv[4] * wb.x + (float)hv[5] * wb.y + (float)hv[6] * wb.z + (float)hv[7] * wb.w;
        }
#pragma unroll
        for (int off = 32; off > 0; off >>= 1) s += __shfl_down(s, off, 64);
        if (lane == 0) dout[((size_t)myb * TT + (t - 1)) * TOUT + 8] = s + bcombo[8];
      }
    }

    // ---- wait-window work 2: x-part of gates(t+1) into fresh acc ----
    acc00 = (f32x4){0.f, 0.f, 0.f, 0.f};
    acc01 = (f32x4){0.f, 0.f, 0.f, 0.f};
    acc10 = (f32x4){0.f, 0.f, 0.f, 0.f};
    acc11 = (f32x4){0.f, 0.f, 0.f, 0.f};
    if (kh == 0 && t + 1 < TT) XPART(t + 1);

    // ---- flat poll: wave 0 lanes 0..7 watch all 8 group counters + inv ----
    if (wv == 0) {
      const unsigned tgt = (unsigned)(t + 1) * 8u;
      unsigned guard = 0;
      bool ab = false;
      for (;;) {
        unsigned v = tgt;
        if (lane < 8)
          v = __hip_atomic_load(qbase + lane * 32, __ATOMIC_RELAXED, __HIP_MEMORY_SCOPE_AGENT);
        if (__all((int)(v >= tgt))) break;
        __builtin_amdgcn_s_sleep(1);
        ++guard;
        unsigned af = 0;
        if ((guard & 255u) == 0u && lane == 0)
          af = __hip_atomic_load(gabort, __ATOMIC_RELAXED, __HIP_MEMORY_SCOPE_AGENT);
        if (__any((int)(af != 0u))) { ab = true; break; }
        if (guard > 200000u) {
          if (lane == 0)
            __hip_atomic_store(gabort, 1u, __ATOMIC_RELAXED, __HIP_MEMORY_SCOPE_AGENT);
          ab = true; break;
        }
      }
      if (lane == 0) {
        if (ab) {
          sAbort = 1;
        } else {
          // ACQUIRE load: emits buffer_inv (invalidate stale L1/L2), no wbl2.
          (void)__hip_atomic_load(qbase, __ATOMIC_ACQUIRE, __HIP_MEMORY_SCOPE_AGENT);
        }
      }
    }
    __syncthreads();
    if (sAbort) return;   // wrong answer beats a wedged GPU

    const _Float16* tp = ha; ha = hn; hn = (_Float16*)tp;
  }

  // ---- epilogue: out(TT-1) for this block's batch from final h ----
  {
    const _Float16* hxb = ha + (size_t)myb * 8;
    {
      const float* wcp = Wc + (size_t)wv * 1024;
      float s = 0.f;
#pragma unroll
      for (int p = 0; p < 2; ++p) {
        int ch = 2 * lane + p;
        half8 hv = *(const half8*)(hxb + (size_t)ch * CH);
        float4 wa = *(const float4*)(wcp + ch * 8);
        float4 wb = *(const float4*)(wcp + ch * 8 + 4);
        s += (float)hv[0] * wa.x + (float)hv[1] * wa.y + (float)hv[2] * wa.z + (float)hv[3] * wa.w
           + (float)hv[4] * wb.x + (float)hv[5] * wb.y + (float)hv[6] * wb.z + (float)hv[7] * wb.w;
      }
#pragma unroll
      for (int off = 32; off > 0; off >>= 1) s += __shfl_down(s, off, 64);
      if (lane == 0) dout[((size_t)myb * TT + (TT - 1)) * TOUT + wv] = s + bcombo[wv];
    }
    if (wv == 0) {
      const float* wcp = Wc + 8 * 1024;
      float s = 0.f;
#pragma unroll
      for (int p = 0; p < 2; ++p) {
        int ch = 2 * lane + p;
        half8 hv = *(const half8*)(hxb + (size_t)ch * CH);
        float4 wa = *(const float4*)(wcp + ch * 8);
        float4 wb = *(const float4*)(wcp + ch * 8 + 4);
        s += (float)hv[0] * wa.x + (float)hv[1] * wa.y + (float)hv[2] * wa.z + (float)hv[3] * wa.w
           + (float)hv[4] * wb.x + (float)hv[5] * wb.y + (float)hv[6] * wb.z + (float)hv[7] * wb.w;
      }
#pragma unroll
      for (int off = 32; off > 0; off >>= 1) s += __shfl_down(s, off, 64);
      if (lane == 0) dout[((size_t)myb * TT + (TT - 1)) * TOUT + 8] = s + bcombo[8];
    }
  }
}

// ---------------- launch ----------------

extern "C" void kernel_launch(void* const* d_in, const int* in_sizes, int n_in,
                              void* d_out, int out_size, void* d_ws, size_t ws_size,
                              hipStream_t stream) {
  if (ws_size < OB_END) return;   // clean fail, no OOB

  const float* x     = (const float*)d_in[0];
  const float* W_ih  = (const float*)d_in[1];
  const float* b_ih  = (const float*)d_in[2];
  const float* W_hh  = (const float*)d_in[3];
  const float* b_hh  = (const float*)d_in[4];
  const float* W_h2h = (const float*)d_in[5];
  const float* b_h2h = (const float*)d_in[6];
  const float* W_h2o = (const float*)d_in[7];
  const float* b_h2o = (const float*)d_in[8];
  const int*   lens  = (const int*)d_in[9];

  char* ws = (char*)d_ws;
  float* dout    = (float*)d_out;
  _Float16* Whf  = (_Float16*)(ws + OB_WHF);
  float* Wcombo  = (float*)(ws + OB_WCB);
  float* bcombo  = (float*)(ws + OB_BCB);
  float* b0      = (float*)(ws + OB_B0);
  float* bconst  = (float*)(ws + OB_BC);
  _Float16* h0   = (_Float16*)(ws + OB_H0);
  _Float16* h1   = (_Float16*)(ws + OB_H1);
  unsigned* gs   = (unsigned*)(ws + OB_GC);

  // zero hx ping-pong + barrier counters every call (graph-replay safe)
  hipMemsetAsync((void*)(ws + OB_H0), 0, OB_END - OB_H0, stream);

  k_combo<<<36, 256, 0, stream>>>(W_h2o, W_h2h, b_h2h, b_h2o, Wcombo, bcombo);
  k_wblk<<<1024, 256, 0, stream>>>(W_hh, W_ih, W_h2o, W_h2h, Whf);
  k_bias<<<16, 256, 0, stream>>>(b_ih, b_hh, W_hh, W_ih, b_h2h, bcombo, b0, bconst);
  k_fillx<<<2048, 256, 0, stream>>>(W_ih, Whf);
  k_len<<<1, 256, 0, stream>>>(lens, dout);

  k_main<<<256, 512, 0, stream>>>(x, Whf, Wcombo, b0, bconst, bcombo, h0, h1, gs, dout);
}

// Round 18
// 4773.943 us; speedup vs baseline: 1.6163x; 1.0020x over previous
//
#include <hip/hip_runtime.h>
#include <math.h>

#define TB 256      // batch
#define TT 512      // timesteps
#define TIN 128     // input size
#define TH 1024     // hidden
#define TOUT 9      // output coords
#define KD 1152     // TIN + TH

typedef _Float16 half8 __attribute__((ext_vector_type(8)));
typedef float f32x4 __attribute__((ext_vector_type(4)));

// ---- workspace layout (BYTE offsets) ----
#define OB_WHF   0ull
#define SB_WHF   (64ull*4*36*64*8*2)    // 9,437,184 B  f16 B-fragments [wcg2][nt][kc][l][j]
#define OB_WCB   (OB_WHF + SB_WHF)      // Wcombo fp32 [9][1024]
#define SB_WCB   (9ull*1024*4)
#define OB_BCB   (OB_WCB + SB_WCB)      // bcombo fp32 [9] (pad 16)
#define SB_BCB   64ull
#define OB_B0    (OB_BCB + SB_BCB)      // bias t==0 [4096] fp32
#define SB_B0    (4096ull*4)
#define OB_BC    (OB_B0 + SB_B0)        // bias t>0  [4096] fp32
#define SB_BC    (4096ull*4)
#define OB_H0    (OB_BC + SB_BC)        // hx ping [128 chunk][256 b][8] f16 (chunk-major)
#define SB_H     (256ull*1024*2)
#define OB_H1    (OB_H0 + SB_H)         // hx pong
#define OB_GC    (OB_H1 + SB_H)         // barrier counters (4 quarters x 2KB)
#define OB_END   (OB_GC + 8192ull)      // ~10.5 MB total

// fragment address for gate col `col` (0..4095), k (0..1151)
// block wcg2 = (col&1023)>>4 owns 16 h-cols; local col c = q*16 + jj, nt = q
__device__ __forceinline__ size_t frag_addr(int col, int k) {
  int q = col >> 10, hcol = col & 1023;
  int wcg2 = hcol >> 4, jj = hcol & 15;
  int kc = k >> 5, ls = (k >> 3) & 3, je = k & 7;
  return ((((size_t)wcg2 * 4 + q) * 36 + kc) * 64 + ((ls << 4) | jj)) * 8 + je;
}

// ---- agent-scope (LLC write-through) 2B h store ----
__device__ __forceinline__ void st_h2_agent(_Float16* p, _Float16 v) {
  union { _Float16 h; unsigned short u; } c; c.h = v;
  __hip_atomic_store((unsigned short*)p, c.u, __ATOMIC_RELAXED, __HIP_MEMORY_SCOPE_AGENT);
}

// ---------------- prep kernels (r5-r17 verified) ----------------

__global__ __launch_bounds__(256) void k_combo(const float* __restrict__ W_h2o,
                                               const float* __restrict__ W_h2h,
                                               const float* __restrict__ b_h2h,
                                               const float* __restrict__ b_h2o,
                                               float* __restrict__ Wcombo,
                                               float* __restrict__ bcombo) {
  int gid = blockIdx.x * 256 + threadIdx.x;
  if (gid < 9 * 1024) {
    int r = gid >> 10, m = gid & 1023;
    float s = 0.f;
    for (int j = 0; j < 1024; ++j) s += W_h2o[r * 1024 + j] * W_h2h[j * 1024 + m];
    Wcombo[gid] = s;
  }
  if (gid < 9) {
    float s = b_h2o[gid];
    for (int j = 0; j < 1024; ++j) s += W_h2o[gid * 1024 + j] * b_h2h[j];
    bcombo[gid] = s;
  }
}

__global__ __launch_bounds__(256) void k_wblk(const float* __restrict__ W_hh,
                                              const float* __restrict__ W_ih,
                                              const float* __restrict__ W_h2o,
                                              const float* __restrict__ W_h2h,
                                              _Float16* __restrict__ Whf) {
  __shared__ float As2[16][68];
  __shared__ float Bs[16][68];
  __shared__ float Wio_s[64][12];
  __shared__ float Bo[9][16];
  const int tid = threadIdx.x;
  const int bm = (blockIdx.x & 15) * 64;   // m tile
  const int bc = (blockIdx.x >> 4) * 64;   // col tile
  const int tx = tid & 15, ty = tid >> 4;
  const int cl = tid >> 2, kq4 = tid & 3;

  for (int i = tid; i < 64 * 9; i += 256) {
    int row = i / 9, r = i % 9;
    Wio_s[row][r] = W_ih[(size_t)(bc + row) * 137 + 128 + r];
  }

  float acc[4][4];
#pragma unroll
  for (int i = 0; i < 4; ++i)
#pragma unroll
    for (int j = 0; j < 4; ++j) acc[i][j] = 0.f;

  for (int k0 = 0; k0 < 1024; k0 += 16) {
    __syncthreads();
    if (tid < 144) { int r = tid >> 4, kk = tid & 15; Bo[r][kk] = W_h2o[(size_t)r * 1024 + k0 + kk]; }
    { int kk = tid >> 4, q = tid & 15;
      float4 v = *(const float4*)(W_h2h + (size_t)(k0 + kk) * 1024 + bm + q * 4);
      *(float4*)&Bs[kk][q * 4] = v; }
    float4 av = *(const float4*)(W_hh + (size_t)(bc + cl) * 1024 + k0 + kq4 * 4);
    __syncthreads();
    {
      float c0 = 0.f, c1 = 0.f, c2 = 0.f, c3 = 0.f;
#pragma unroll
      for (int r = 0; r < 9; ++r) {
        float wio = Wio_s[cl][r];
        c0 += wio * Bo[r][kq4 * 4 + 0];
        c1 += wio * Bo[r][kq4 * 4 + 1];
        c2 += wio * Bo[r][kq4 * 4 + 2];
        c3 += wio * Bo[r][kq4 * 4 + 3];
      }
      As2[kq4 * 4 + 0][cl] = av.x + c0;
      As2[kq4 * 4 + 1][cl] = av.y + c1;
      As2[kq4 * 4 + 2][cl] = av.z + c2;
      As2[kq4 * 4 + 3][cl] = av.w + c3;
    }
    __syncthreads();
#pragma unroll
    for (int kk = 0; kk < 16; ++kk) {
      float4 a = *(const float4*)&As2[kk][ty * 4];
      float4 bv = *(const float4*)&Bs[kk][tx * 4];
      acc[0][0] += a.x * bv.x; acc[0][1] += a.x * bv.y; acc[0][2] += a.x * bv.z; acc[0][3] += a.x * bv.w;
      acc[1][0] += a.y * bv.x; acc[1][1] += a.y * bv.y; acc[1][2] += a.y * bv.z; acc[1][3] += a.y * bv.w;
      acc[2][0] += a.z * bv.x; acc[2][1] += a.z * bv.y; acc[2][2] += a.z * bv.z; acc[2][3] += a.z * bv.w;
      acc[3][0] += a.w * bv.x; acc[3][1] += a.w * bv.y; acc[3][2] += a.w * bv.z; acc[3][3] += a.w * bv.w;
    }
  }
#pragma unroll
  for (int i = 0; i < 4; ++i)
#pragma unroll
    for (int j = 0; j < 4; ++j) {
      int col = bc + ty * 4 + i;          // gate col
      int m = bm + tx * 4 + j;            // h index -> k = 128+m
      Whf[frag_addr(col, 128 + m)] = (_Float16)acc[i][j];
    }
}

__global__ __launch_bounds__(256) void k_bias(const float* __restrict__ b_ih,
                                              const float* __restrict__ b_hh,
                                              const float* __restrict__ W_hh,
                                              const float* __restrict__ W_ih,
                                              const float* __restrict__ b_h2h,
                                              const float* __restrict__ bcombo,
                                              float* __restrict__ b0,
                                              float* __restrict__ bconst) {
  int col = blockIdx.x * 256 + threadIdx.x;
  float base = b_ih[col] + b_hh[col];
  b0[col] = base;
  float s = 0.f;
  for (int j = 0; j < 1024; ++j) s += W_hh[(size_t)col * 1024 + j] * b_h2h[j];
#pragma unroll
  for (int r = 0; r < 9; ++r) s += W_ih[(size_t)col * 137 + 128 + r] * bcombo[r];
  bconst[col] = base + s;
}

__global__ __launch_bounds__(256) void k_fillx(const float* __restrict__ W_ih,
                                               _Float16* __restrict__ Whf) {
  int gid = blockIdx.x * 256 + threadIdx.x;   // 4096*128
  int col = gid >> 7, k = gid & 127;
  Whf[frag_addr(col, k)] = (_Float16)W_ih[(size_t)col * 137 + k];
}

__global__ void k_len(const int* __restrict__ len, float* __restrict__ dout) {
  int i = threadIdx.x;
  if (i < TB) dout[(size_t)TB * TT * TOUT + i] = (float)len[i];
}

// ---------------- persistent main kernel ----------------
// r17 structure (4 independent quarters, 16 h-cols/block, Wl 147KB LDS,
// chunk-major hx, 2B write-through stores, cached reads + invalidate-only
// ACQUIRE, KEEP-pinned prefetch, flat barrier) with 3 chain micro-cuts:
//   (1) no redundant __threadfence_block (syncthreads drains vmcnt);
//   (2) arrival RMW by tid 511 (wave 7) -> overlaps wave 0's poll;
//   (3) XPART (cold x loads) issued before out-GEMV in the wait window.

__device__ __forceinline__ float sigm(float v) { return 1.f / (1.f + __expf(-v)); }
__device__ __forceinline__ float tanh_f(float v) {
  float e2 = __expf(2.f * v);
  return (e2 - 1.f) / (e2 + 1.f);
}

#define KEEP14(a) asm volatile("" :: "v"(a[0]), "v"(a[1]), "v"(a[2]), "v"(a[3]), \
  "v"(a[4]), "v"(a[5]), "v"(a[6]), "v"(a[7]), "v"(a[8]), "v"(a[9]), "v"(a[10]), \
  "v"(a[11]), "v"(a[12]), "v"(a[13]))
#define KEEP18(a) asm volatile("" :: "v"(a[0]), "v"(a[1]), "v"(a[2]), "v"(a[3]), \
  "v"(a[4]), "v"(a[5]), "v"(a[6]), "v"(a[7]), "v"(a[8]), "v"(a[9]), "v"(a[10]), \
  "v"(a[11]), "v"(a[12]), "v"(a[13]), "v"(a[14]), "v"(a[15]), "v"(a[16]), "v"(a[17]))

__global__ __launch_bounds__(512, 2) void k_main(const float* __restrict__ x,
                                                 const _Float16* __restrict__ Whf,
                                                 const float* __restrict__ Wc,
                                                 const float* __restrict__ b0,
                                                 const float* __restrict__ bcf,
                                                 const float* __restrict__ bcombo,
                                                 _Float16* __restrict__ hA,
                                                 _Float16* __restrict__ hB,
                                                 unsigned* __restrict__ gs,
                                                 float* __restrict__ dout) {
  __shared__ _Float16 Wl[4 * 36 * 64 * 8];   // 147,456 B (64 gate cols)
  __shared__ _Float16 gbuf[64][72];          //   9,216 B
  __shared__ int sAbort;

  const int bx = blockIdx.x;
  const int qd = bx >> 6;            // quarter 0..3 (independent)
  const int wcg2 = bx & 63;          // col-group: h-cols 16*wcg2..+15
  const int B0 = qd * 64;            // batch base
  const int myb = B0 + wcg2;         // this block's out-GEMV batch
  const int grp = wcg2 >> 3;         // barrier group within quarter (8 groups x 8)
  const int tid = threadIdx.x;
  const int lane = tid & 63;
  const int wv = tid >> 6;           // 0..7
  const int mp = wv & 1, np = (wv >> 1) & 1, kh = wv >> 2;

  const size_t CH = (size_t)TB * 8;  // halfwords per 8-col chunk

  unsigned* qbase = gs + qd * 512;           // per-quarter barrier region (2KB)
  unsigned* gcnt_grp = qbase + grp * 32;     // arrival counter (own 128B line)
  unsigned* gabort = gs + 500;               // global abort flag (quarter0 tail)

  {  // stage this block's 64-col W slice (147,456 B) into LDS once
    const uint4* src = (const uint4*)(Whf + (size_t)wcg2 * (4 * 36 * 64 * 8));
    uint4* dst = (uint4*)Wl;
    for (int i = tid; i < 4 * 36 * 64 * 8 / 8; i += 512) dst[i] = src[i];
  }
  if (tid == 0) sAbort = 0;

  // bias registers for finish: cols fj and fj+8, 4 gates each, bconst + b0
  const int fb_i = tid >> 3, fj_i = tid & 7;
  const int cb = wcg2 * 16;
  float bC0 = bcf[cb + fj_i],          bC1 = bcf[1024 + cb + fj_i];
  float bC2 = bcf[2048 + cb + fj_i],   bC3 = bcf[3072 + cb + fj_i];
  float bC4 = bcf[cb + 8 + fj_i],      bC5 = bcf[1024 + cb + 8 + fj_i];
  float bC6 = bcf[2048 + cb + 8 + fj_i], bC7 = bcf[3072 + cb + 8 + fj_i];
  float bZ0 = b0[cb + fj_i],           bZ1 = b0[1024 + cb + fj_i];
  float bZ2 = b0[2048 + cb + fj_i],    bZ3 = b0[3072 + cb + fj_i];
  float bZ4 = b0[cb + 8 + fj_i],       bZ5 = b0[1024 + cb + 8 + fj_i];
  float bZ6 = b0[2048 + cb + 8 + fj_i], bZ7 = b0[3072 + cb + 8 + fj_i];
  float cs0 = 0.f, cs1 = 0.f;   // cell states for (fb_i, col fj_i) and (fb_i, col fj_i+8)
  __syncthreads();

  const _Float16* ha = hA;   // hx(t-1), zeroed by memset
  _Float16* hn = hB;

  const int bA0 = B0 + mp * 32 + (lane & 15);  // A row, M-tile 2mp
  const int bA1 = bA0 + 16;                    // A row, M-tile 2mp+1
  const int ko = (lane >> 4) * 8;              // A k offset within 32-chunk
  const int chb = lane >> 4;                   // chunk sub-offset (ko/8)
  const _Float16* wlb0 = Wl + (size_t)(2 * np) * 18432 + (size_t)lane * 8;
  const _Float16* wlb1 = wlb0 + 18432;

  // persistent accumulators: x-part(t) computed during t-1's barrier wait
  f32x4 acc00 = {0.f, 0.f, 0.f, 0.f};
  f32x4 acc01 = {0.f, 0.f, 0.f, 0.f};
  f32x4 acc10 = {0.f, 0.f, 0.f, 0.f};
  f32x4 acc11 = {0.f, 0.f, 0.f, 0.f};

#define XPART(tt) do { \
    const float* x0_ = x + ((size_t)bA0 * TT + (tt)) * TIN; \
    const float* x1_ = x + ((size_t)bA1 * TT + (tt)) * TIN; \
    _Pragma("unroll") \
    for (int i_ = 0; i_ < 4; ++i_) { \
      float4 p0 = *(const float4*)(x0_ + i_ * 32 + ko); \
      float4 p1 = *(const float4*)(x0_ + i_ * 32 + ko + 4); \
      float4 q0 = *(const float4*)(x1_ + i_ * 32 + ko); \
      float4 q1 = *(const float4*)(x1_ + i_ * 32 + ko + 4); \
      half8 v0_, v1_; \
      v0_[0] = (_Float16)p0.x; v0_[1] = (_Float16)p0.y; v0_[2] = (_Float16)p0.z; v0_[3] = (_Float16)p0.w; \
      v0_[4] = (_Float16)p1.x; v0_[5] = (_Float16)p1.y; v0_[6] = (_Float16)p1.z; v0_[7] = (_Float16)p1.w; \
      v1_[0] = (_Float16)q0.x; v1_[1] = (_Float16)q0.y; v1_[2] = (_Float16)q0.z; v1_[3] = (_Float16)q0.w; \
      v1_[4] = (_Float16)q1.x; v1_[5] = (_Float16)q1.y; v1_[6] = (_Float16)q1.z; v1_[7] = (_Float16)q1.w; \
      half8 bf0_ = *(const half8*)(wlb0 + (size_t)i_ * 512); \
      half8 bf1_ = *(const half8*)(wlb1 + (size_t)i_ * 512); \
      acc00 = __builtin_amdgcn_mfma_f32_16x16x32_f16(v0_, bf0_, acc00, 0, 0, 0); \
      acc01 = __builtin_amdgcn_mfma_f32_16x16x32_f16(v0_, bf1_, acc01, 0, 0, 0); \
      acc10 = __builtin_amdgcn_mfma_f32_16x16x32_f16(v1_, bf0_, acc10, 0, 0, 0); \
      acc11 = __builtin_amdgcn_mfma_f32_16x16x32_f16(v1_, bf1_, acc11, 0, 0, 0); \
    } \
  } while (0)

  if (kh == 0) XPART(0);   // t=0's x-part (h(-1)=0)

  for (int t = 0; t < TT; ++t) {
    // ---- h-fragment prefetch (cached, post-inv), pinned live via asm ----
    const _Float16* hb0 = ha + (size_t)chb * CH + (size_t)bA0 * 8;
    const _Float16* hb1 = ha + (size_t)chb * CH + (size_t)bA1 * 8;
    if (kh == 0) {
      half8 a0[14], a1[14];
#pragma unroll
      for (int i = 0; i < 14; ++i) {            // kcg = 4+i, chunk 4*i (+chb)
        a0[i] = *(const half8*)(hb0 + (size_t)(4 * i) * CH);
        a1[i] = *(const half8*)(hb1 + (size_t)(4 * i) * CH);
      }
      KEEP14(a0); KEEP14(a1);
      __builtin_amdgcn_sched_barrier(0);
#pragma unroll
      for (int i = 0; i < 14; ++i) {
        const int kcg = 4 + i;
        half8 bf0 = *(const half8*)(wlb0 + (size_t)kcg * 512);
        half8 bf1 = *(const half8*)(wlb1 + (size_t)kcg * 512);
        acc00 = __builtin_amdgcn_mfma_f32_16x16x32_f16(a0[i], bf0, acc00, 0, 0, 0);
        acc01 = __builtin_amdgcn_mfma_f32_16x16x32_f16(a0[i], bf1, acc01, 0, 0, 0);
        acc10 = __builtin_amdgcn_mfma_f32_16x16x32_f16(a1[i], bf0, acc10, 0, 0, 0);
        acc11 = __builtin_amdgcn_mfma_f32_16x16x32_f16(a1[i], bf1, acc11, 0, 0, 0);
      }
    } else {
      half8 a0[18], a1[18];
#pragma unroll
      for (int i = 0; i < 18; ++i) {            // kcg = 18+i, chunk 4*i+56
        a0[i] = *(const half8*)(hb0 + (size_t)(4 * i + 56) * CH);
        a1[i] = *(const half8*)(hb1 + (size_t)(4 * i + 56) * CH);
      }
      KEEP18(a0); KEEP18(a1);
      __builtin_amdgcn_sched_barrier(0);
#pragma unroll
      for (int i = 0; i < 18; ++i) {
        const int kcg = 18 + i;
        half8 bf0 = *(const half8*)(wlb0 + (size_t)kcg * 512);
        half8 bf1 = *(const half8*)(wlb1 + (size_t)kcg * 512);
        acc00 = __builtin_amdgcn_mfma_f32_16x16x32_f16(a0[i], bf0, acc00, 0, 0, 0);
        acc01 = __builtin_amdgcn_mfma_f32_16x16x32_f16(a0[i], bf1, acc01, 0, 0, 0);
        acc10 = __builtin_amdgcn_mfma_f32_16x16x32_f16(a1[i], bf0, acc10, 0, 0, 0);
        acc11 = __builtin_amdgcn_mfma_f32_16x16x32_f16(a1[i], bf1, acc11, 0, 0, 0);
      }
    }
    // ---- two-phase gbuf reduction: kh0 writes, kh1 adds ----
    {
      int rb0 = mp * 32 + (lane >> 4) * 4;
      int rb1 = rb0 + 16;
      int cc0 = np * 32 + (lane & 15);
      int cc1 = cc0 + 16;
      if (kh == 0) {
#pragma unroll
        for (int r = 0; r < 4; ++r) {
          gbuf[rb0 + r][cc0] = (_Float16)acc00[r];
          gbuf[rb0 + r][cc1] = (_Float16)acc01[r];
          gbuf[rb1 + r][cc0] = (_Float16)acc10[r];
          gbuf[rb1 + r][cc1] = (_Float16)acc11[r];
        }
      }
      __syncthreads();
      if (kh == 1) {
#pragma unroll
        for (int r = 0; r < 4; ++r) {
          gbuf[rb0 + r][cc0] = (_Float16)((float)gbuf[rb0 + r][cc0] + acc00[r]);
          gbuf[rb0 + r][cc1] = (_Float16)((float)gbuf[rb0 + r][cc1] + acc01[r]);
          gbuf[rb1 + r][cc0] = (_Float16)((float)gbuf[rb1 + r][cc0] + acc10[r]);
          gbuf[rb1 + r][cc1] = (_Float16)((float)gbuf[rb1 + r][cc1] + acc11[r]);
        }
      }
      __syncthreads();
    }

    // ---- LSTM finish: thread (fb_i, fj_i) handles cols fj_i and fj_i+8 ----
    {
      const bool later = (t > 0);
      float b_0 = later ? bC0 : bZ0, b_1 = later ? bC1 : bZ1;
      float b_2 = later ? bC2 : bZ2, b_3 = later ? bC3 : bZ3;
      float b_4 = later ? bC4 : bZ4, b_5 = later ? bC5 : bZ5;
      float b_6 = later ? bC6 : bZ6, b_7 = later ? bC7 : bZ7;
      float vi = (float)gbuf[fb_i][fj_i]      + b_0;
      float vf = (float)gbuf[fb_i][16 + fj_i] + b_1;
      float vg = (float)gbuf[fb_i][32 + fj_i] + b_2;
      float vo = (float)gbuf[fb_i][48 + fj_i] + b_3;
      float ig = sigm(vi), fg = sigm(vf), gg = tanh_f(vg), og = sigm(vo);
      float cn = fg * cs0 + ig * gg;
      cs0 = cn;
      st_h2_agent(hn + (size_t)(2 * wcg2) * CH + (size_t)(B0 + fb_i) * 8 + fj_i,
                  (_Float16)(og * tanh_f(cn)));
      float vi2 = (float)gbuf[fb_i][8 + fj_i]  + b_4;
      float vf2 = (float)gbuf[fb_i][24 + fj_i] + b_5;
      float vg2 = (float)gbuf[fb_i][40 + fj_i] + b_6;
      float vo2 = (float)gbuf[fb_i][56 + fj_i] + b_7;
      float ig2 = sigm(vi2), fg2 = sigm(vf2), gg2 = tanh_f(vg2), og2 = sigm(vo2);
      float cn2 = fg2 * cs1 + ig2 * gg2;
      cs1 = cn2;
      st_h2_agent(hn + (size_t)(2 * wcg2 + 1) * CH + (size_t)(B0 + fb_i) * 8 + fj_i,
                  (_Float16)(og2 * tanh_f(cn2)));
    }
    __syncthreads();   // emits s_waitcnt vmcnt(0) per thread: stores at LLC

    // ---- flat barrier arrival: RMW by wave 7 (overlaps wave 0's poll) ----
    if (tid == 511)
      __hip_atomic_fetch_add(gcnt_grp, 1u, __ATOMIC_RELAXED, __HIP_MEMORY_SCOPE_AGENT);

    // ---- wait-window work 1: x-part of gates(t+1) (cold x loads first) ----
    acc00 = (f32x4){0.f, 0.f, 0.f, 0.f};
    acc01 = (f32x4){0.f, 0.f, 0.f, 0.f};
    acc10 = (f32x4){0.f, 0.f, 0.f, 0.f};
    acc11 = (f32x4){0.f, 0.f, 0.f, 0.f};
    if (kh == 0 && t + 1 < TT) XPART(t + 1);

    // ---- wait-window work 2: out(t-1) GEMV (cached h, cached Wc) ----
    if (t > 0) {
      const _Float16* hxb = ha + (size_t)myb * 8;
      {
        const float* wcp = Wc + (size_t)wv * 1024;
        float s = 0.f;
#pragma unroll
        for (int p = 0; p < 2; ++p) {
          int ch = 2 * lane + p;
          half8 hv = *(const half8*)(hxb + (size_t)ch * CH);
          float4 wa = *(const float4*)(wcp + ch * 8);
          float4 wb = *(const float4*)(wcp + ch * 8 + 4);
          s += (float)hv[0] * wa.x + (float)hv[1] * wa.y + (float)hv[2] * wa.z + (float)hv[3] * wa.w
             + (float)hv[4] * wb.x + (float)hv[5] * wb.y + (float)hv[6] * wb.z + (float)hv[7] * wb.w;
        }
#pragma unroll
        for (int off = 32; off > 0; off >>= 1) s += __shfl_down(s, off, 64);
        if (lane == 0) dout[((size_t)myb * TT + (t - 1)) * TOUT + wv] = s + bcombo[wv];
      }
      if (wv == 0) {
        const float* wcp = Wc + 8 * 1024;
        float s = 0.f;
#pragma unroll
        for (int p = 0; p < 2; ++p) {
          int ch = 2 * lane + p;
          half8 hv = *(const half8*)(hxb + (size_t)ch * CH);
          float4 wa = *(const float4*)(wcp + ch * 8);
          float4 wb = *(const float4*)(wcp + ch * 8 + 4);
          s += (float)hv[0] * wa.x + (float)hv[1] * wa.y + (float)hv[2] * wa.z + (float)hv[3] * wa.w
             + (float)hv[4] * wb.x + (float)hv[5] * wb.y + (float)hv[6] * wb.z + (float)hv[7] * wb.w;
        }
#pragma unroll
        for (int off = 32; off > 0; off >>= 1) s += __shfl_down(s, off, 64);
        if (lane == 0) dout[((size_t)myb * TT + (t - 1)) * TOUT + 8] = s + bcombo[8];
      }
    }

    // ---- flat poll: wave 0 lanes 0..7 watch all 8 group counters + inv ----
    if (wv == 0) {
      const unsigned tgt = (unsigned)(t + 1) * 8u;
      unsigned guard = 0;
      bool ab = false;
      for (;;) {
        unsigned v = tgt;
        if (lane < 8)
          v = __hip_atomic_load(qbase + lane * 32, __ATOMIC_RELAXED, __HIP_MEMORY_SCOPE_AGENT);
        if (__all((int)(v >= tgt))) break;
        __builtin_amdgcn_s_sleep(1);
        ++guard;
        unsigned af = 0;
        if ((guard & 255u) == 0u && lane == 0)
          af = __hip_atomic_load(gabort, __ATOMIC_RELAXED, __HIP_MEMORY_SCOPE_AGENT);
        if (__any((int)(af != 0u))) { ab = true; break; }
        if (guard > 200000u) {
          if (lane == 0)
            __hip_atomic_store(gabort, 1u, __ATOMIC_RELAXED, __HIP_MEMORY_SCOPE_AGENT);
          ab = true; break;
        }
      }
      if (lane == 0) {
        if (ab) {
          sAbort = 1;
        } else {
          // ACQUIRE load: emits buffer_inv (invalidate stale L1/L2), no wbl2.
          (void)__hip_atomic_load(qbase, __ATOMIC_ACQUIRE, __HIP_MEMORY_SCOPE_AGENT);
        }
      }
    }
    __syncthreads();
    if (sAbort) return;   // wrong answer beats a wedged GPU

    const _Float16* tp = ha; ha = hn; hn = (_Float16*)tp;
  }

  // ---- epilogue: out(TT-1) for this block's batch from final h ----
  {
    const _Float16* hxb = ha + (size_t)myb * 8;
    {
      const float* wcp = Wc + (size_t)wv * 1024;
      float s = 0.f;
#pragma unroll
      for (int p = 0; p < 2; ++p) {
        int ch = 2 * lane + p;
        half8 hv = *(const half8*)(hxb + (size_t)ch * CH);
        float4 wa = *(const float4*)(wcp + ch * 8);
        float4 wb = *(const float4*)(wcp + ch * 8 + 4);
        s += (float)hv[0] * wa.x + (float)hv[1] * wa.y + (float)hv[2] * wa.z + (float)hv[3] * wa.w
           + (float)hv[4] * wb.x + (float)hv[5] * wb.y + (float)hv[6] * wb.z + (float)hv[7] * wb.w;
      }
#pragma unroll
      for (int off = 32; off > 0; off >>= 1) s += __shfl_down(s, off, 64);
      if (lane == 0) dout[((size_t)myb * TT + (TT - 1)) * TOUT + wv] = s + bcombo[wv];
    }
    if (wv == 0) {
      const float* wcp = Wc + 8 * 1024;
      float s = 0.f;
#pragma unroll
      for (int p = 0; p < 2; ++p) {
        int ch = 2 * lane + p;
        half8 hv = *(const half8*)(hxb + (size_t)ch * CH);
        float4 wa = *(const float4*)(wcp + ch * 8);
        float4 wb = *(const float4*)(wcp + ch * 8 + 4);
        s += (float)hv[0] * wa.x + (float)hv[1] * wa.y + (float)hv[2] * wa.z + (float)hv[3] * wa.w
           + (float)hv[4] * wb.x + (float)hv[5] * wb.y + (float)hv[6] * wb.z + (float)hv[7] * wb.w;
      }
#pragma unroll
      for (int off = 32; off > 0; off >>= 1) s += __shfl_down(s, off, 64);
      if (lane == 0) dout[((size_t)myb * TT + (TT - 1)) * TOUT + 8] = s + bcombo[8];
    }
  }
}

// ---------------- launch ----------------

extern "C" void kernel_launch(void* const* d_in, const int* in_sizes, int n_in,
                              void* d_out, int out_size, void* d_ws, size_t ws_size,
                              hipStream_t stream) {
  if (ws_size < OB_END) return;   // clean fail, no OOB

  const float* x     = (const float*)d_in[0];
  const float* W_ih  = (const float*)d_in[1];
  const float* b_ih  = (const float*)d_in[2];
  const float* W_hh  = (const float*)d_in[3];
  const float* b_hh  = (const float*)d_in[4];
  const float* W_h2h = (const float*)d_in[5];
  const float* b_h2h = (const float*)d_in[6];
  const float* W_h2o = (const float*)d_in[7];
  const float* b_h2o = (const float*)d_in[8];
  const int*   lens  = (const int*)d_in[9];

  char* ws = (char*)d_ws;
  float* dout    = (float*)d_out;
  _Float16* Whf  = (_Float16*)(ws + OB_WHF);
  float* Wcombo  = (float*)(ws + OB_WCB);
  float* bcombo  = (float*)(ws + OB_BCB);
  float* b0      = (float*)(ws + OB_B0);
  float* bconst  = (float*)(ws + OB_BC);
  _Float16* h0   = (_Float16*)(ws + OB_H0);
  _Float16* h1   = (_Float16*)(ws + OB_H1);
  unsigned* gs   = (unsigned*)(ws + OB_GC);

  // zero hx ping-pong + barrier counters every call (graph-replay safe)
  hipMemsetAsync((void*)(ws + OB_H0), 0, OB_END - OB_H0, stream);

  k_combo<<<36, 256, 0, stream>>>(W_h2o, W_h2h, b_h2h, b_h2o, Wcombo, bcombo);
  k_wblk<<<1024, 256, 0, stream>>>(W_hh, W_ih, W_h2o, W_h2h, Whf);
  k_bias<<<16, 256, 0, stream>>>(b_ih, b_hh, W_hh, W_ih, b_h2h, bcombo, b0, bconst);
  k_fillx<<<2048, 256, 0, stream>>>(W_ih, Whf);
  k_len<<<1, 256, 0, stream>>>(lens, dout);

  k_main<<<256, 512, 0, stream>>>(x, Whf, Wcombo, b0, bconst, bcombo, h0, h1, gs, dout);
}